// Round 4
// baseline (2084.015 us; speedup 1.0000x reference)
//
#include <hip/hip_runtime.h>

#define NN 100000
#define NE 1600000
#define HID 64
#define MSG_IN 156   // 2*64 + 2*6 + 16
#define W1E_OFF 140  // rows: [0:64) h_src, [64:128) h_dst, [128:134) sc_src, [134:140) sc_dst, [140:156) ef
#define NBLK_D 1563            // ceil(NN/64) dst-blocks
#define NSB 49                 // src buckets: src>>11 -> 0..48
#define KEYS (NBLK_D * NSB)    // 76587 composite sort keys

__device__ __forceinline__ void mm4x4(float (&acc)[4][4], const float4 a, const float4 b) {
    acc[0][0] = fmaf(a.x, b.x, acc[0][0]);
    acc[0][1] = fmaf(a.x, b.y, acc[0][1]);
    acc[0][2] = fmaf(a.x, b.z, acc[0][2]);
    acc[0][3] = fmaf(a.x, b.w, acc[0][3]);
    acc[1][0] = fmaf(a.y, b.x, acc[1][0]);
    acc[1][1] = fmaf(a.y, b.y, acc[1][1]);
    acc[1][2] = fmaf(a.y, b.z, acc[1][2]);
    acc[1][3] = fmaf(a.y, b.w, acc[1][3]);
    acc[2][0] = fmaf(a.z, b.x, acc[2][0]);
    acc[2][1] = fmaf(a.z, b.y, acc[2][1]);
    acc[2][2] = fmaf(a.z, b.z, acc[2][2]);
    acc[2][3] = fmaf(a.z, b.w, acc[2][3]);
    acc[3][0] = fmaf(a.w, b.x, acc[3][0]);
    acc[3][1] = fmaf(a.w, b.y, acc[3][1]);
    acc[3][2] = fmaf(a.w, b.z, acc[3][2]);
    acc[3][3] = fmaf(a.w, b.w, acc[3][3]);
}

// ---------------- edge preprocessing ----------------

// fallback-tier only
__global__ __launch_bounds__(256) void k_sw(
    const int2* __restrict__ el2, const float* __restrict__ ew,
    float* __restrict__ sw, int n_edges)
{
    int e = blockIdx.x * 256 + threadIdx.x;
    if (e < n_edges) atomicAdd(&sw[el2[e].y], ew[e]);
}

// composite-key histogram fused with sw accumulation
__global__ __launch_bounds__(256) void k_hist2(
    const int2* __restrict__ el2, const float* __restrict__ ew,
    int* __restrict__ counts, float* __restrict__ sw, int n_edges)
{
    int e = blockIdx.x * 256 + threadIdx.x;
    if (e < n_edges) {
        int2 sd = el2[e];
        atomicAdd(&counts[(sd.y >> 6) * NSB + (sd.x >> 11)], 1);
        atomicAdd(&sw[sd.y], ew[e]);
    }
}

// in-place-safe block exclusive scan (offs may alias counts)
__global__ __launch_bounds__(256) void k_scan1(
    const int* counts, int* offs, int* __restrict__ blksum, int n)
{
    __shared__ int s[256];
    const int tid = threadIdx.x;
    int i = blockIdx.x * 256 + tid;
    int v = (i < n) ? counts[i] : 0;
    s[tid] = v;
    for (int off = 1; off < 256; off <<= 1) {
        __syncthreads();
        int t = (tid >= off) ? s[tid - off] : 0;
        __syncthreads();
        s[tid] += t;
    }
    __syncthreads();
    if (i < n) offs[i] = s[tid] - v;
    if (tid == 255) blksum[blockIdx.x] = s[255];
}

__global__ __launch_bounds__(512) void k_scan2(int* __restrict__ blksum, int nb)
{
    __shared__ int s[512];
    const int tid = threadIdx.x;
    int v = (tid < nb) ? blksum[tid] : 0;
    s[tid] = v;
    for (int off = 1; off < 512; off <<= 1) {
        __syncthreads();
        int t = (tid >= off) ? s[tid - off] : 0;
        __syncthreads();
        s[tid] += t;
    }
    __syncthreads();
    if (tid < nb) blksum[tid] = s[tid] - v;
}

__global__ __launch_bounds__(256) void k_scan3(
    int* __restrict__ offs, const int* __restrict__ blksum, int n)
{
    int i = blockIdx.x * 256 + threadIdx.x;
    if (i < n) offs[i] += blksum[blockIdx.x];
}

__global__ __launch_bounds__(256) void k_permute2(
    const int2* __restrict__ el2, int* __restrict__ cursor,
    int* __restrict__ perm, int n_edges)
{
    int e = blockIdx.x * 256 + threadIdx.x;
    if (e < n_edges) {
        int2 sd = el2[e];
        int key = (sd.y >> 6) * NSB + (sd.x >> 11);
        int pos = atomicAdd(&cursor[key], 1);
        perm[pos] = e;
    }
    // after this kernel, cursor[key] == end offset of key's edge range
}

// C_l = msg_w2_l @ U1b_l ; db_l = msg_b2_l @ U1b_l   (U1b = upd_w1 rows 64..127)
__global__ __launch_bounds__(256) void k_csmall(
    const float* __restrict__ msg_w2, const float* __restrict__ upd_w1,
    const float* __restrict__ msg_b2, float* __restrict__ C2, float* __restrict__ db2)
{
    const int l = blockIdx.x;
    const float* W2  = msg_w2 + (size_t)l * 4096;
    const float* U1b = upd_w1 + (size_t)l * 8192 + 4096;
    const float* b2  = msg_b2 + l * 64;
    float* C  = C2  + (size_t)l * 4096;
    float* db = db2 + l * 64;
    __shared__ __align__(16) float At[64][68];
    __shared__ __align__(16) float B[64][64];
    const int tid = threadIdx.x;
    for (int i = tid; i < 1024; i += 256) {
        ((float4*)B)[i] = ((const float4*)U1b)[i];
        int m = i >> 4, f4 = i & 15, k4 = f4 * 4;
        float4 v = ((const float4*)W2)[m * 16 + f4];
        At[k4 + 0][m] = v.x; At[k4 + 1][m] = v.y; At[k4 + 2][m] = v.z; At[k4 + 3][m] = v.w;
    }
    __syncthreads();
    const int ty = tid >> 4, tx = tid & 15;
    float acc[4][4];
    #pragma unroll
    for (int r = 0; r < 4; ++r) { acc[r][0]=0.f; acc[r][1]=0.f; acc[r][2]=0.f; acc[r][3]=0.f; }
    #pragma unroll 8
    for (int k = 0; k < 64; ++k) {
        float4 a = *(const float4*)&At[k][ty * 4];
        float4 bv = *(const float4*)&B[k][tx * 4];
        mm4x4(acc, a, bv);
    }
    #pragma unroll
    for (int r = 0; r < 4; ++r)
        ((float4*)C)[(ty * 4 + r) * 16 + tx] = make_float4(acc[r][0], acc[r][1], acc[r][2], acc[r][3]);
    if (tid < 64) {
        float sum = 0.f;
        for (int k = 0; k < 64; ++k) sum += b2[k] * B[k][tid];
        db[tid] = sum;
    }
}

// ---------------- dense per-tile GEMM kernels ----------------

// h = x @ lin_w + lin_b
__global__ __launch_bounds__(256) void k_init(
    const float* __restrict__ x, const float* __restrict__ w,
    const float* __restrict__ b, float* __restrict__ h, int n)
{
    __shared__ __align__(16) float At[64][68];
    __shared__ __align__(16) float B[64][64];
    const int tid = threadIdx.x;
    const int m0 = blockIdx.x * 64;
    for (int i = tid; i < 1024; i += 256)
        ((float4*)B)[i] = ((const float4*)w)[i];
    for (int i = tid; i < 1024; i += 256) {
        int m = i >> 4, f4 = i & 15, k4 = f4 * 4;
        int node = m0 + m;
        float4 v = make_float4(0.f, 0.f, 0.f, 0.f);
        if (node < n) v = ((const float4*)x)[node * 16 + f4];
        At[k4 + 0][m] = v.x; At[k4 + 1][m] = v.y; At[k4 + 2][m] = v.z; At[k4 + 3][m] = v.w;
    }
    __syncthreads();
    const int ty = tid >> 4, tx = tid & 15;
    float acc[4][4];
    {
        float4 bb = ((const float4*)b)[tx];
        #pragma unroll
        for (int r = 0; r < 4; ++r) { acc[r][0]=bb.x; acc[r][1]=bb.y; acc[r][2]=bb.z; acc[r][3]=bb.w; }
    }
    #pragma unroll 8
    for (int k = 0; k < 64; ++k) {
        float4 a = *(const float4*)&At[k][ty * 4];
        float4 bv = *(const float4*)&B[k][tx * 4];
        mm4x4(acc, a, bv);
    }
    #pragma unroll
    for (int r = 0; r < 4; ++r) {
        int node = m0 + ty * 4 + r;
        if (node < n)
            ((float4*)h)[node * 16 + tx] = make_float4(acc[r][0], acc[r][1], acc[r][2], acc[r][3]);
    }
}

// p = h@W1a + sc@W1c ; q = h@W1b + sc@W1d + b1
__global__ __launch_bounds__(256) void k_pq(
    const float* __restrict__ h, const int* __restrict__ nsc,
    const float* __restrict__ w1, const float* __restrict__ b1,
    float* __restrict__ p, float* __restrict__ q, int n)
{
    __shared__ __align__(16) float At[64][68];
    __shared__ __align__(16) float Bp[64][64];
    __shared__ __align__(16) float Bq[64][64];
    __shared__ __align__(16) float Sct[6][68];
    __shared__ __align__(16) float Bc[6][64];
    __shared__ __align__(16) float Bd[6][64];
    const int tid = threadIdx.x;
    const int m0 = blockIdx.x * 64;
    for (int i = tid; i < 1024; i += 256) {
        ((float4*)Bp)[i] = ((const float4*)w1)[i];
        ((float4*)Bq)[i] = ((const float4*)(w1 + 64 * 64))[i];
    }
    if (tid < 96) {
        ((float4*)Bc)[tid] = ((const float4*)(w1 + 128 * 64))[tid];
        ((float4*)Bd)[tid] = ((const float4*)(w1 + 134 * 64))[tid];
    }
    for (int i = tid; i < 1024; i += 256) {
        int m = i >> 4, f4 = i & 15, k4 = f4 * 4;
        int node = m0 + m;
        float4 v = make_float4(0.f, 0.f, 0.f, 0.f);
        if (node < n) v = ((const float4*)h)[node * 16 + f4];
        At[k4 + 0][m] = v.x; At[k4 + 1][m] = v.y; At[k4 + 2][m] = v.z; At[k4 + 3][m] = v.w;
    }
    for (int i = tid; i < 384; i += 256) {
        int m = i & 63, k = i >> 6;
        int node = m0 + m;
        float v = 0.f;
        if (node < n) v = (float)nsc[node * 6 + k];
        Sct[k][m] = v;
    }
    __syncthreads();
    const int ty = tid >> 4, tx = tid & 15;
    float ap[4][4], aq[4][4];
    {
        float4 bb = ((const float4*)b1)[tx];
        #pragma unroll
        for (int r = 0; r < 4; ++r) {
            ap[r][0]=0.f; ap[r][1]=0.f; ap[r][2]=0.f; ap[r][3]=0.f;
            aq[r][0]=bb.x; aq[r][1]=bb.y; aq[r][2]=bb.z; aq[r][3]=bb.w;
        }
    }
    #pragma unroll 8
    for (int k = 0; k < 64; ++k) {
        float4 a  = *(const float4*)&At[k][ty * 4];
        float4 bp = *(const float4*)&Bp[k][tx * 4];
        float4 bq = *(const float4*)&Bq[k][tx * 4];
        mm4x4(ap, a, bp);
        mm4x4(aq, a, bq);
    }
    #pragma unroll
    for (int k = 0; k < 6; ++k) {
        float4 a  = *(const float4*)&Sct[k][ty * 4];
        float4 bc = *(const float4*)&Bc[k][tx * 4];
        float4 bd = *(const float4*)&Bd[k][tx * 4];
        mm4x4(ap, a, bc);
        mm4x4(aq, a, bd);
    }
    #pragma unroll
    for (int r = 0; r < 4; ++r) {
        int node = m0 + ty * 4 + r;
        if (node < n) {
            ((float4*)p)[node * 16 + tx] = make_float4(ap[r][0], ap[r][1], ap[r][2], ap[r][3]);
            ((float4*)q)[node * 16 + tx] = make_float4(aq[r][0], aq[r][1], aq[r][2], aq[r][3]);
        }
    }
}

// CSR edge kernel (R1 structure, composite-sorted edge order):
// block owns dsts [b*64, b*64+64) and ALL their edges; 64-edge chunks staged
// cooperatively in LDS; hid = relu(p[src]+q[dst]+ef@W1e); per-dst sums in LDS
// Sacc via ds atomics (order-free), written to S with plain float4 stores.
// Composite key (dst>>6, src>>11) makes the p-gather sweep src monotonically
// -> cross-block L2/L3 reuse of 256B p rows.
__global__ __launch_bounds__(256) void k_edge_csr(
    const int* __restrict__ perm, const int* __restrict__ kends,
    const int2* __restrict__ el2,
    const float* __restrict__ ew, const float* __restrict__ ef,
    const float* __restrict__ p, const float* __restrict__ q,
    const float* __restrict__ w1e, float* __restrict__ S, int n_nodes)
{
    __shared__ __align__(16) float Et[16][68];
    __shared__ __align__(16) float W1e[16][64];
    __shared__ __align__(16) float Sacc[64][68];
    __shared__ int Ssrc[64];
    __shared__ int Sdst[64];
    __shared__ float Sew[64];
    const int tid = threadIdx.x;
    int b = blockIdx.x;
    {   // bijective XCD-chunked swizzle (works for any nb)
        const int nb = gridDim.x;
        const int qn = nb >> 3, rr = nb & 7;
        const int xcd = b & 7, idx = b >> 3;
        b = (xcd < rr ? xcd * (qn + 1) : rr * (qn + 1) + (xcd - rr) * qn) + idx;
    }
    const int d0 = b * 64;
    const int dn = min(64, n_nodes - d0);
    const int kbase = b * NSB;
    const int eStart = (b == 0) ? 0 : kends[kbase - 1];
    const int eEnd   = kends[kbase + NSB - 1];

    ((float4*)W1e)[tid] = ((const float4*)w1e)[tid];
    for (int i = tid; i < 64 * 17; i += 256)       // zero Sacc (64*68 floats)
        ((float4*)Sacc)[i] = make_float4(0.f, 0.f, 0.f, 0.f);

    const int ty = tid >> 4, tx = tid & 15;

    for (int c0 = eStart; c0 < eEnd; c0 += 64) {
        __syncthreads();   // covers Sacc-zero on iter0; protects stage bufs after
        if (tid < 64) {
            int e = c0 + tid;
            int s = 0, d = d0; float w = 0.f;
            if (e < eEnd) {
                int pe = perm[e];
                int2 sd = el2[pe];
                s = sd.x; d = sd.y; w = ew[pe];
            }
            Ssrc[tid] = s; Sdst[tid] = d; Sew[tid] = w;
        }
        {
            int e = tid >> 2, f4 = tid & 3, k4 = f4 * 4;
            int ge = c0 + e;
            float4 v = make_float4(0.f, 0.f, 0.f, 0.f);
            if (ge < eEnd) {
                int pe = perm[ge];                 // 4 lanes share one perm read
                v = ((const float4*)ef)[(size_t)pe * 4 + f4];
            }
            Et[k4 + 0][e] = v.x; Et[k4 + 1][e] = v.y; Et[k4 + 2][e] = v.z; Et[k4 + 3][e] = v.w;
        }
        __syncthreads();
        float acc[4][4];
        #pragma unroll
        for (int r = 0; r < 4; ++r) {
            int s = Ssrc[ty * 4 + r], d = Sdst[ty * 4 + r];
            float4 pv = ((const float4*)p)[(size_t)s * 16 + tx];
            float4 qv = ((const float4*)q)[(size_t)d * 16 + tx];   // block-local dst range
            acc[r][0] = pv.x + qv.x; acc[r][1] = pv.y + qv.y;
            acc[r][2] = pv.z + qv.z; acc[r][3] = pv.w + qv.w;
        }
        #pragma unroll
        for (int k = 0; k < 16; ++k) {
            float4 a = *(const float4*)&Et[k][ty * 4];
            float4 bv = *(const float4*)&W1e[k][tx * 4];
            mm4x4(acc, a, bv);
        }
        // direct LDS atomics (dst not sorted within the composite-key order)
        #pragma unroll
        for (int r = 0; r < 4; ++r) {
            int le = ty * 4 + r;
            if (c0 + le < eEnd) {
                int d = Sdst[le];
                float w = Sew[le];
                float* dp = &Sacc[d - d0][tx * 4];
                atomicAdd(dp + 0, fmaxf(acc[r][0], 0.f) * w);
                atomicAdd(dp + 1, fmaxf(acc[r][1], 0.f) * w);
                atomicAdd(dp + 2, fmaxf(acc[r][2], 0.f) * w);
                atomicAdd(dp + 3, fmaxf(acc[r][3], 0.f) * w);
            }
        }
    }
    __syncthreads();
    for (int i = tid; i < dn * 16; i += 256) {
        int row = i >> 4, f4 = i & 15;
        ((float4*)S)[(size_t)(d0 + row) * 16 + f4] = *(const float4*)&Sacc[row][f4 * 4];
    }
}

// fallback (no-sort tier): tile kernel with global atomics
__global__ __launch_bounds__(256) void k_edge2(
    const int* __restrict__ perm, const int2* __restrict__ el2,
    const float* __restrict__ ew, const float* __restrict__ ef,
    const float* __restrict__ p, const float* __restrict__ q,
    const float* __restrict__ w1e, float* __restrict__ S, int n_edges)
{
    __shared__ __align__(16) float Et[16][68];
    __shared__ __align__(16) float W1e[16][64];
    __shared__ int Ssrc[64];
    __shared__ int Sdst[64];
    __shared__ float Sew[64];
    const int tid = threadIdx.x;
    const int b = blockIdx.x, nb = gridDim.x;
    const int tile = ((nb & 7) == 0) ? ((b & 7) * (nb >> 3) + (b >> 3)) : b;
    const int e0 = tile * 64;
    if (tid < 64) {
        int e = e0 + tid;
        int s = 0, d = 0; float w = 0.f;
        if (e < n_edges) {
            int pe = perm ? perm[e] : e;
            int2 sd = el2[pe];
            s = sd.x; d = sd.y; w = ew[pe];
        }
        Ssrc[tid] = s; Sdst[tid] = d; Sew[tid] = w;
    }
    ((float4*)W1e)[tid] = ((const float4*)w1e)[tid];
    {
        int e = tid >> 2, f4 = tid & 3, k4 = f4 * 4;
        int ge = e0 + e;
        float4 v = make_float4(0.f, 0.f, 0.f, 0.f);
        if (ge < n_edges) {
            int pe = perm ? perm[ge] : ge;
            v = ((const float4*)ef)[(size_t)pe * 4 + f4];
        }
        Et[k4 + 0][e] = v.x; Et[k4 + 1][e] = v.y; Et[k4 + 2][e] = v.z; Et[k4 + 3][e] = v.w;
    }
    __syncthreads();
    const int ty = tid >> 4, tx = tid & 15;
    float acc[4][4];
    #pragma unroll
    for (int r = 0; r < 4; ++r) {
        int s = Ssrc[ty * 4 + r], d = Sdst[ty * 4 + r];
        float4 pv = ((const float4*)p)[(size_t)s * 16 + tx];
        float4 qv = ((const float4*)q)[(size_t)d * 16 + tx];
        acc[r][0] = pv.x + qv.x; acc[r][1] = pv.y + qv.y;
        acc[r][2] = pv.z + qv.z; acc[r][3] = pv.w + qv.w;
    }
    #pragma unroll
    for (int k = 0; k < 16; ++k) {
        float4 a = *(const float4*)&Et[k][ty * 4];
        float4 bv = *(const float4*)&W1e[k][tx * 4];
        mm4x4(acc, a, bv);
    }
    {
        int curd = -1;
        float s0 = 0.f, s1 = 0.f, s2 = 0.f, s3 = 0.f;
        #pragma unroll
        for (int r = 0; r < 4; ++r) {
            int le = ty * 4 + r;
            int ge = e0 + le;
            if (ge < n_edges) {
                int d = Sdst[le];
                float w = Sew[le];
                float v0 = fmaxf(acc[r][0], 0.f) * w;
                float v1 = fmaxf(acc[r][1], 0.f) * w;
                float v2 = fmaxf(acc[r][2], 0.f) * w;
                float v3 = fmaxf(acc[r][3], 0.f) * w;
                if (d != curd) {
                    if (curd >= 0) {
                        atomicAdd(&S[(size_t)curd * 64 + tx * 4 + 0], s0);
                        atomicAdd(&S[(size_t)curd * 64 + tx * 4 + 1], s1);
                        atomicAdd(&S[(size_t)curd * 64 + tx * 4 + 2], s2);
                        atomicAdd(&S[(size_t)curd * 64 + tx * 4 + 3], s3);
                    }
                    curd = d; s0 = v0; s1 = v1; s2 = v2; s3 = v3;
                } else {
                    s0 += v0; s1 += v1; s2 += v2; s3 += v3;
                }
            }
        }
        if (curd >= 0) {
            atomicAdd(&S[(size_t)curd * 64 + tx * 4 + 0], s0);
            atomicAdd(&S[(size_t)curd * 64 + tx * 4 + 1], s1);
            atomicAdd(&S[(size_t)curd * 64 + tx * 4 + 2], s2);
            atomicAdd(&S[(size_t)curd * 64 + tx * 4 + 3], s3);
        }
    }
}

// h = relu(relu(h@U1a + S@C + sw*db + ub1)@uw2 + ub2); optional fused graph segsum
__global__ __launch_bounds__(256) void k_update(
    float* __restrict__ h, const float* __restrict__ S,
    const float* __restrict__ w1, const float* __restrict__ C,
    const float* __restrict__ b1, const float* __restrict__ w2,
    const float* __restrict__ b2, const float* __restrict__ db,
    const float* __restrict__ sw,
    int n, int write_out, float* __restrict__ out_graph,
    const int* __restrict__ n2g)
{
    __shared__ __align__(16) float At[64][68];
    __shared__ __align__(16) float B1[128][64];
    __shared__ float Db[64];
    const int tid = threadIdx.x;
    const int m0 = blockIdx.x * 64;
    const int ty = tid >> 4, tx = tid & 15;
    if (tid < 64) Db[tid] = db[tid];
    for (int i = tid; i < 2048; i += 256)
        ((float4*)B1)[i] = (i < 1024) ? ((const float4*)w1)[i] : ((const float4*)C)[i - 1024];
    for (int i = tid; i < 1024; i += 256) {
        int m = i >> 4, f4 = i & 15, k4 = f4 * 4;
        int node = m0 + m;
        float4 v = make_float4(0.f, 0.f, 0.f, 0.f);
        if (node < n) v = ((const float4*)h)[node * 16 + f4];
        At[k4 + 0][m] = v.x; At[k4 + 1][m] = v.y; At[k4 + 2][m] = v.z; At[k4 + 3][m] = v.w;
    }
    __syncthreads();
    float acc[4][4];
    {
        float4 bb = ((const float4*)b1)[tx];
        #pragma unroll
        for (int r = 0; r < 4; ++r) { acc[r][0]=bb.x; acc[r][1]=bb.y; acc[r][2]=bb.z; acc[r][3]=bb.w; }
    }
    #pragma unroll 8
    for (int k = 0; k < 64; ++k) {
        float4 a = *(const float4*)&At[k][ty * 4];
        float4 bv = *(const float4*)&B1[k][tx * 4];
        mm4x4(acc, a, bv);
    }
    __syncthreads();
    for (int i = tid; i < 1024; i += 256) {
        int m = i >> 4, f4 = i & 15, k4 = f4 * 4;
        int node = m0 + m;
        float4 v = make_float4(0.f, 0.f, 0.f, 0.f);
        if (node < n) v = ((const float4*)S)[node * 16 + f4];
        At[k4 + 0][m] = v.x; At[k4 + 1][m] = v.y; At[k4 + 2][m] = v.z; At[k4 + 3][m] = v.w;
    }
    __syncthreads();
    #pragma unroll 8
    for (int k = 0; k < 64; ++k) {
        float4 a = *(const float4*)&At[k][ty * 4];
        float4 bv = *(const float4*)&B1[64 + k][tx * 4];
        mm4x4(acc, a, bv);
    }
    #pragma unroll
    for (int r = 0; r < 4; ++r) {
        int node = m0 + ty * 4 + r;
        float swv = (node < n) ? sw[node] : 0.f;
        #pragma unroll
        for (int c = 0; c < 4; ++c)
            acc[r][c] = fmaf(swv, Db[tx * 4 + c], acc[r][c]);
    }
    __syncthreads();
    #pragma unroll
    for (int r = 0; r < 4; ++r)
        #pragma unroll
        for (int c = 0; c < 4; ++c)
            At[tx * 4 + c][ty * 4 + r] = fmaxf(acc[r][c], 0.f);
    for (int i = tid; i < 1024; i += 256)
        ((float4*)B1)[i] = ((const float4*)w2)[i];
    __syncthreads();
    float acc2[4][4];
    {
        float4 bb = ((const float4*)b2)[tx];
        #pragma unroll
        for (int r = 0; r < 4; ++r) { acc2[r][0]=bb.x; acc2[r][1]=bb.y; acc2[r][2]=bb.z; acc2[r][3]=bb.w; }
    }
    #pragma unroll 8
    for (int k = 0; k < 64; ++k) {
        float4 a = *(const float4*)&At[k][ty * 4];
        float4 bv = *(const float4*)&B1[k][tx * 4];
        mm4x4(acc2, a, bv);
    }
    float hv[4][4];
    #pragma unroll
    for (int r = 0; r < 4; ++r)
        #pragma unroll
        for (int c = 0; c < 4; ++c)
            hv[r][c] = fmaxf(acc2[r][c], 0.f);
    #pragma unroll
    for (int r = 0; r < 4; ++r) {
        int node = m0 + ty * 4 + r;
        if (node < n)
            ((float4*)h)[node * 16 + tx] = make_float4(hv[r][0], hv[r][1], hv[r][2], hv[r][3]);
    }
    if (write_out) {
        int curg = -1;
        float s0 = 0.f, s1 = 0.f, s2 = 0.f, s3 = 0.f;
        #pragma unroll
        for (int r = 0; r < 4; ++r) {
            int node = m0 + ty * 4 + r;
            if (node < n) {
                int g = n2g[node];
                if (g != curg) {
                    if (curg >= 0) {
                        atomicAdd(&out_graph[curg * 64 + tx * 4 + 0], s0);
                        atomicAdd(&out_graph[curg * 64 + tx * 4 + 1], s1);
                        atomicAdd(&out_graph[curg * 64 + tx * 4 + 2], s2);
                        atomicAdd(&out_graph[curg * 64 + tx * 4 + 3], s3);
                    }
                    curg = g; s0 = hv[r][0]; s1 = hv[r][1]; s2 = hv[r][2]; s3 = hv[r][3];
                } else {
                    s0 += hv[r][0]; s1 += hv[r][1]; s2 += hv[r][2]; s3 += hv[r][3];
                }
            }
        }
        if (curg >= 0) {
            atomicAdd(&out_graph[curg * 64 + tx * 4 + 0], s0);
            atomicAdd(&out_graph[curg * 64 + tx * 4 + 1], s1);
            atomicAdd(&out_graph[curg * 64 + tx * 4 + 2], s2);
            atomicAdd(&out_graph[curg * 64 + tx * 4 + 3], s3);
        }
    }
}

extern "C" void kernel_launch(void* const* d_in, const int* in_sizes, int n_in,
                              void* d_out, int out_size, void* d_ws, size_t ws_size,
                              hipStream_t stream)
{
    const float* x       = (const float*)d_in[0];
    const int2*  el2     = (const int2*)d_in[1];
    const int*   nsc     = (const int*)d_in[2];
    const float* ef      = (const float*)d_in[3];
    const float* ew      = (const float*)d_in[4];
    const int*   n2g     = (const int*)d_in[5];
    const float* lin_w   = (const float*)d_in[7];
    const float* lin_b   = (const float*)d_in[8];
    const float* msg_w1  = (const float*)d_in[9];
    const float* msg_b1  = (const float*)d_in[10];
    const float* msg_w2  = (const float*)d_in[11];
    const float* upd_w1  = (const float*)d_in[13];
    const float* upd_b1  = (const float*)d_in[14];
    const float* upd_w2  = (const float*)d_in[15];
    const float* upd_b2  = (const float*)d_in[16];
    const float* msg_b2  = (const float*)d_in[12];

    float* out_graph = (float*)d_out;              // 128*64
    float* h   = (float*)d_out + 128 * 64;         // node_feature region doubles as h

    const size_t NNH = (size_t)NN * HID;
    float* p  = (float*)d_ws;                     // 25.6 MB
    float* q  = p + NNH;                          // 25.6 MB
    float* S  = q + NNH;                          // 25.6 MB
    char*  cur = (char*)(S + NNH);
    const size_t base   = 3 * NNH * sizeof(float);         // 76.8 MB
    const size_t szPerm = (size_t)NE * sizeof(int);        //  6.4 MB
    const size_t szCnt  = (size_t)NN * sizeof(int);        //  0.4 MB (>= KEYS ints)
    const size_t szSw   = (size_t)NN * sizeof(float);      //  0.4 MB
    const size_t szBlk  = 4096;
    const size_t szC    = 2 * 64 * 64 * sizeof(float);     // 32 KB
    const size_t szDb   = 2 * 64 * sizeof(float);
    const size_t need_sort = base + szPerm + szCnt + szBlk + szSw + szC + szDb; // ~84.04 MB

    int *perm = nullptr, *counts = nullptr, *blksum = nullptr;
    float *sw, *C2, *db2;
    const int do_sort = (ws_size >= need_sort) ? 1 : 0;
    if (do_sort) {
        perm   = (int*)cur;        cur += szPerm;
        counts = (int*)cur;        cur += szCnt;
        blksum = (int*)cur;        cur += szBlk;
    }
    sw  = (float*)cur;             cur += szSw;
    C2  = (float*)cur;             cur += szC;
    db2 = (float*)cur;

    const int nblk_n  = (NN + 63) / 64;            // 1563 = NBLK_D
    const int nblk_e  = (NE + 63) / 64;
    const int nblk_eh = (NE + 255) / 256;
    const int nblk_k  = (KEYS + 255) / 256;        // 300 <= 512

    hipMemsetAsync(d_out, 0, 128 * 64 * sizeof(float), stream);
    hipMemsetAsync(sw, 0, szSw, stream);

    if (do_sort) {
        hipMemsetAsync(counts, 0, szCnt, stream);
        k_hist2<<<nblk_eh, 256, 0, stream>>>(el2, ew, counts, sw, NE);   // fused sw
        k_scan1<<<nblk_k, 256, 0, stream>>>(counts, counts, blksum, KEYS);
        k_scan2<<<1, 512, 0, stream>>>(blksum, nblk_k);
        k_scan3<<<nblk_k, 256, 0, stream>>>(counts, blksum, KEYS);
        k_permute2<<<nblk_eh, 256, 0, stream>>>(el2, counts, perm, NE);
        // counts[key] now == end offset of key's range
    } else {
        k_sw<<<nblk_eh, 256, 0, stream>>>(el2, ew, sw, NE);
    }
    k_csmall<<<2, 256, 0, stream>>>(msg_w2, upd_w1, msg_b2, C2, db2);

    k_init<<<nblk_n, 256, 0, stream>>>(x, lin_w, lin_b, h, NN);
    for (int l = 0; l < 2; ++l) {
        const float* w1 = msg_w1 + (size_t)l * MSG_IN * HID;
        k_pq<<<nblk_n, 256, 0, stream>>>(h, nsc, w1, msg_b1 + l * HID, p, q, NN);
        if (do_sort) {
            k_edge_csr<<<nblk_n, 256, 0, stream>>>(perm, counts, el2, ew, ef, p, q,
                                                   w1 + W1E_OFF * HID, S, NN);
        } else {
            hipMemsetAsync(S, 0, NNH * sizeof(float), stream);
            k_edge2<<<nblk_e, 256, 0, stream>>>(nullptr, el2, ew, ef, p, q,
                                                w1 + W1E_OFF * HID, S, NE);
        }
        k_update<<<nblk_n, 256, 0, stream>>>(h, S,
                                             upd_w1 + (size_t)l * 2 * HID * HID,
                                             C2 + (size_t)l * 4096,
                                             upd_b1 + l * HID,
                                             upd_w2 + (size_t)l * HID * HID,
                                             upd_b2 + l * HID,
                                             db2 + l * 64, sw,
                                             NN, (l == 1) ? 1 : 0, out_graph, n2g);
    }
}

// Round 5
// 1178.246 us; speedup vs baseline: 1.7687x; 1.7687x over previous
//
#include <hip/hip_runtime.h>

#define NN 100000
#define NE 1600000
#define HID 64
#define MSG_IN 156   // 2*64 + 2*6 + 16
#define W1E_OFF 140  // rows: [0:64) h_src, [64:128) h_dst, [128:134) sc_src, [134:140) sc_dst, [140:156) ef

__device__ __forceinline__ void mm4x4(float (&acc)[4][4], const float4 a, const float4 b) {
    acc[0][0] = fmaf(a.x, b.x, acc[0][0]);
    acc[0][1] = fmaf(a.x, b.y, acc[0][1]);
    acc[0][2] = fmaf(a.x, b.z, acc[0][2]);
    acc[0][3] = fmaf(a.x, b.w, acc[0][3]);
    acc[1][0] = fmaf(a.y, b.x, acc[1][0]);
    acc[1][1] = fmaf(a.y, b.y, acc[1][1]);
    acc[1][2] = fmaf(a.y, b.z, acc[1][2]);
    acc[1][3] = fmaf(a.y, b.w, acc[1][3]);
    acc[2][0] = fmaf(a.z, b.x, acc[2][0]);
    acc[2][1] = fmaf(a.z, b.y, acc[2][1]);
    acc[2][2] = fmaf(a.z, b.z, acc[2][2]);
    acc[2][3] = fmaf(a.z, b.w, acc[2][3]);
    acc[3][0] = fmaf(a.w, b.x, acc[3][0]);
    acc[3][1] = fmaf(a.w, b.y, acc[3][1]);
    acc[3][2] = fmaf(a.w, b.z, acc[3][2]);
    acc[3][3] = fmaf(a.w, b.w, acc[3][3]);
}

// ---------------- edge preprocessing (dst-sort tier) ----------------

// fallback-tier only
__global__ __launch_bounds__(256) void k_sw(
    const int2* __restrict__ el2, const float* __restrict__ ew,
    float* __restrict__ sw, int n_edges)
{
    int e = blockIdx.x * 256 + threadIdx.x;
    if (e < n_edges) atomicAdd(&sw[el2[e].y], ew[e]);
}

// dst histogram fused with sw accumulation (saves one 1.6M-edge pass)
__global__ __launch_bounds__(256) void k_hist2(
    const int2* __restrict__ el2, const float* __restrict__ ew,
    int* __restrict__ counts, float* __restrict__ sw, int n_edges)
{
    int e = blockIdx.x * 256 + threadIdx.x;
    if (e < n_edges) {
        int2 sd = el2[e];
        atomicAdd(&counts[sd.y], 1);
        atomicAdd(&sw[sd.y], ew[e]);
    }
}

// in-place-safe block exclusive scan (offs may alias counts)
__global__ __launch_bounds__(256) void k_scan1(
    const int* counts, int* offs, int* __restrict__ blksum, int n)
{
    __shared__ int s[256];
    const int tid = threadIdx.x;
    int i = blockIdx.x * 256 + tid;
    int v = (i < n) ? counts[i] : 0;
    s[tid] = v;
    for (int off = 1; off < 256; off <<= 1) {
        __syncthreads();
        int t = (tid >= off) ? s[tid - off] : 0;
        __syncthreads();
        s[tid] += t;
    }
    __syncthreads();
    if (i < n) offs[i] = s[tid] - v;
    if (tid == 255) blksum[blockIdx.x] = s[255];
}

__global__ __launch_bounds__(512) void k_scan2(int* __restrict__ blksum, int nb)
{
    __shared__ int s[512];
    const int tid = threadIdx.x;
    int v = (tid < nb) ? blksum[tid] : 0;
    s[tid] = v;
    for (int off = 1; off < 512; off <<= 1) {
        __syncthreads();
        int t = (tid >= off) ? s[tid - off] : 0;
        __syncthreads();
        s[tid] += t;
    }
    __syncthreads();
    if (tid < nb) blksum[tid] = s[tid] - v;
}

__global__ __launch_bounds__(256) void k_scan3(
    int* __restrict__ offs, const int* __restrict__ blksum, int n)
{
    int i = blockIdx.x * 256 + threadIdx.x;
    if (i < n) offs[i] += blksum[blockIdx.x];
}

__global__ __launch_bounds__(256) void k_permute(
    const int2* __restrict__ el2, int* __restrict__ cursor,
    int* __restrict__ perm, int n_edges)
{
    int e = blockIdx.x * 256 + threadIdx.x;
    if (e < n_edges) {
        int pos = atomicAdd(&cursor[el2[e].y], 1);
        perm[pos] = e;
    }
    // after this kernel, cursor[d] == CSR end offset of dst d
}

// C_l = msg_w2_l @ U1b_l ; db_l = msg_b2_l @ U1b_l   (U1b = upd_w1 rows 64..127)
__global__ __launch_bounds__(256) void k_csmall(
    const float* __restrict__ msg_w2, const float* __restrict__ upd_w1,
    const float* __restrict__ msg_b2, float* __restrict__ C2, float* __restrict__ db2)
{
    const int l = blockIdx.x;
    const float* W2  = msg_w2 + (size_t)l * 4096;
    const float* U1b = upd_w1 + (size_t)l * 8192 + 4096;
    const float* b2  = msg_b2 + l * 64;
    float* C  = C2  + (size_t)l * 4096;
    float* db = db2 + l * 64;
    __shared__ __align__(16) float At[64][68];
    __shared__ __align__(16) float B[64][64];
    const int tid = threadIdx.x;
    for (int i = tid; i < 1024; i += 256) {
        ((float4*)B)[i] = ((const float4*)U1b)[i];
        int m = i >> 4, f4 = i & 15, k4 = f4 * 4;
        float4 v = ((const float4*)W2)[m * 16 + f4];
        At[k4 + 0][m] = v.x; At[k4 + 1][m] = v.y; At[k4 + 2][m] = v.z; At[k4 + 3][m] = v.w;
    }
    __syncthreads();
    const int ty = tid >> 4, tx = tid & 15;
    float acc[4][4];
    #pragma unroll
    for (int r = 0; r < 4; ++r) { acc[r][0]=0.f; acc[r][1]=0.f; acc[r][2]=0.f; acc[r][3]=0.f; }
    #pragma unroll 8
    for (int k = 0; k < 64; ++k) {
        float4 a = *(const float4*)&At[k][ty * 4];
        float4 bv = *(const float4*)&B[k][tx * 4];
        mm4x4(acc, a, bv);
    }
    #pragma unroll
    for (int r = 0; r < 4; ++r)
        ((float4*)C)[(ty * 4 + r) * 16 + tx] = make_float4(acc[r][0], acc[r][1], acc[r][2], acc[r][3]);
    if (tid < 64) {
        float sum = 0.f;
        for (int k = 0; k < 64; ++k) sum += b2[k] * B[k][tid];
        db[tid] = sum;
    }
}

// ---------------- dense per-tile GEMM kernels ----------------

// h = x @ lin_w + lin_b
__global__ __launch_bounds__(256) void k_init(
    const float* __restrict__ x, const float* __restrict__ w,
    const float* __restrict__ b, float* __restrict__ h, int n)
{
    __shared__ __align__(16) float At[64][68];
    __shared__ __align__(16) float B[64][64];
    const int tid = threadIdx.x;
    const int m0 = blockIdx.x * 64;
    for (int i = tid; i < 1024; i += 256)
        ((float4*)B)[i] = ((const float4*)w)[i];
    for (int i = tid; i < 1024; i += 256) {
        int m = i >> 4, f4 = i & 15, k4 = f4 * 4;
        int node = m0 + m;
        float4 v = make_float4(0.f, 0.f, 0.f, 0.f);
        if (node < n) v = ((const float4*)x)[node * 16 + f4];
        At[k4 + 0][m] = v.x; At[k4 + 1][m] = v.y; At[k4 + 2][m] = v.z; At[k4 + 3][m] = v.w;
    }
    __syncthreads();
    const int ty = tid >> 4, tx = tid & 15;
    float acc[4][4];
    {
        float4 bb = ((const float4*)b)[tx];
        #pragma unroll
        for (int r = 0; r < 4; ++r) { acc[r][0]=bb.x; acc[r][1]=bb.y; acc[r][2]=bb.z; acc[r][3]=bb.w; }
    }
    #pragma unroll 8
    for (int k = 0; k < 64; ++k) {
        float4 a = *(const float4*)&At[k][ty * 4];
        float4 bv = *(const float4*)&B[k][tx * 4];
        mm4x4(acc, a, bv);
    }
    #pragma unroll
    for (int r = 0; r < 4; ++r) {
        int node = m0 + ty * 4 + r;
        if (node < n)
            ((float4*)h)[node * 16 + tx] = make_float4(acc[r][0], acc[r][1], acc[r][2], acc[r][3]);
    }
}

// p = h@W1a + sc@W1c ; q = h@W1b + sc@W1d + b1
__global__ __launch_bounds__(256) void k_pq(
    const float* __restrict__ h, const int* __restrict__ nsc,
    const float* __restrict__ w1, const float* __restrict__ b1,
    float* __restrict__ p, float* __restrict__ q, int n)
{
    __shared__ __align__(16) float At[64][68];
    __shared__ __align__(16) float Bp[64][64];
    __shared__ __align__(16) float Bq[64][64];
    __shared__ __align__(16) float Sct[6][68];
    __shared__ __align__(16) float Bc[6][64];
    __shared__ __align__(16) float Bd[6][64];
    const int tid = threadIdx.x;
    const int m0 = blockIdx.x * 64;
    for (int i = tid; i < 1024; i += 256) {
        ((float4*)Bp)[i] = ((const float4*)w1)[i];
        ((float4*)Bq)[i] = ((const float4*)(w1 + 64 * 64))[i];
    }
    if (tid < 96) {
        ((float4*)Bc)[tid] = ((const float4*)(w1 + 128 * 64))[tid];
        ((float4*)Bd)[tid] = ((const float4*)(w1 + 134 * 64))[tid];
    }
    for (int i = tid; i < 1024; i += 256) {
        int m = i >> 4, f4 = i & 15, k4 = f4 * 4;
        int node = m0 + m;
        float4 v = make_float4(0.f, 0.f, 0.f, 0.f);
        if (node < n) v = ((const float4*)h)[node * 16 + f4];
        At[k4 + 0][m] = v.x; At[k4 + 1][m] = v.y; At[k4 + 2][m] = v.z; At[k4 + 3][m] = v.w;
    }
    for (int i = tid; i < 384; i += 256) {
        int m = i & 63, k = i >> 6;
        int node = m0 + m;
        float v = 0.f;
        if (node < n) v = (float)nsc[node * 6 + k];
        Sct[k][m] = v;
    }
    __syncthreads();
    const int ty = tid >> 4, tx = tid & 15;
    float ap[4][4], aq[4][4];
    {
        float4 bb = ((const float4*)b1)[tx];
        #pragma unroll
        for (int r = 0; r < 4; ++r) {
            ap[r][0]=0.f; ap[r][1]=0.f; ap[r][2]=0.f; ap[r][3]=0.f;
            aq[r][0]=bb.x; aq[r][1]=bb.y; aq[r][2]=bb.z; aq[r][3]=bb.w;
        }
    }
    #pragma unroll 8
    for (int k = 0; k < 64; ++k) {
        float4 a  = *(const float4*)&At[k][ty * 4];
        float4 bp = *(const float4*)&Bp[k][tx * 4];
        float4 bq = *(const float4*)&Bq[k][tx * 4];
        mm4x4(ap, a, bp);
        mm4x4(aq, a, bq);
    }
    #pragma unroll
    for (int k = 0; k < 6; ++k) {
        float4 a  = *(const float4*)&Sct[k][ty * 4];
        float4 bc = *(const float4*)&Bc[k][tx * 4];
        float4 bd = *(const float4*)&Bd[k][tx * 4];
        mm4x4(ap, a, bc);
        mm4x4(aq, a, bd);
    }
    #pragma unroll
    for (int r = 0; r < 4; ++r) {
        int node = m0 + ty * 4 + r;
        if (node < n) {
            ((float4*)p)[node * 16 + tx] = make_float4(ap[r][0], ap[r][1], ap[r][2], ap[r][3]);
            ((float4*)q)[node * 16 + tx] = make_float4(aq[r][0], aq[r][1], aq[r][2], aq[r][3]);
        }
    }
}

// ---------------- pipelined CSR edge kernel (dst-sorted) ----------------
// Block owns dsts [b*64,b*64+64) and all their edges (dst-sorted CSR via perm).
// R1's chunk-cooperative tile + register pipeline:
//   perm -> regs 2 chunks ahead; el2/ew -> regs 2 ahead; ef -> LDS dbuf 1 ahead;
//   p[src] -> regs 1 ahead; q[dst] issued before the 16-K GEMM, consumed after.
// Run-length carry (dst-sorted) collapses LDS atomics; S written with plain
// float4 stores (zero global atomics, no S memset). ONE barrier per chunk.

struct Meta { int pe[4]; };
struct El   { int s[4]; int d[4]; float w[4]; };
struct Pv   { float4 pv[4]; };
struct Run  { int d; float s0, s1, s2, s3; };

__device__ __forceinline__ void load_perm(Meta& m, int& spe, int c0, int eEnd,
    int ty, int tid, const int* __restrict__ perm)
{
    #pragma unroll
    for (int r = 0; r < 4; ++r) {
        int e = c0 + ty * 4 + r;
        m.pe[r] = perm[e < eEnd ? e : (eEnd - 1)];
    }
    int es = c0 + (tid >> 2);
    spe = perm[es < eEnd ? es : (eEnd - 1)];
}

__device__ __forceinline__ void load_el(El& e, const Meta& m,
    const int2* __restrict__ el2, const float* __restrict__ ew)
{
    #pragma unroll
    for (int r = 0; r < 4; ++r) {
        int2 sd = el2[m.pe[r]];
        e.s[r] = sd.x; e.d[r] = sd.y; e.w[r] = ew[m.pe[r]];
    }
}

__device__ __forceinline__ void load_p(Pv& z, const El& e,
    const float4* __restrict__ p4, int tx)
{
    #pragma unroll
    for (int r = 0; r < 4; ++r)
        z.pv[r] = p4[(size_t)e.s[r] * 16 + tx];
}

__device__ __forceinline__ void stage_ef(float (*Eb)[68], float4 v, int tid)
{
    int e = tid >> 2, k4 = (tid & 3) * 4;
    Eb[k4 + 0][e] = v.x; Eb[k4 + 1][e] = v.y;
    Eb[k4 + 2][e] = v.z; Eb[k4 + 3][e] = v.w;
}

__device__ __forceinline__ void flush_run(float (*Sacc)[68], const Run& run,
    int d0, int tx)
{
    float* dp = &Sacc[run.d - d0][tx * 4];
    atomicAdd(dp + 0, run.s0); atomicAdd(dp + 1, run.s1);
    atomicAdd(dp + 2, run.s2); atomicAdd(dp + 3, run.s3);
}

__device__ __forceinline__ void compute_chunk(const El& el, const Pv& pvr,
    int c0, int eEnd, int d0, const float (*Eb)[68], const float (*W1e)[64],
    float (*Sacc)[68], const float4* __restrict__ q4, int ty, int tx, Run& run)
{
    float4 qv[4];
    #pragma unroll
    for (int r = 0; r < 4; ++r)                       // issue q loads first
        qv[r] = q4[(size_t)el.d[r] * 16 + tx];
    float acc[4][4];
    #pragma unroll
    for (int r = 0; r < 4; ++r) {                     // init from prefetched p
        acc[r][0] = pvr.pv[r].x; acc[r][1] = pvr.pv[r].y;
        acc[r][2] = pvr.pv[r].z; acc[r][3] = pvr.pv[r].w;
    }
    #pragma unroll
    for (int k = 0; k < 16; ++k) {                    // q latency hides here
        float4 a = *(const float4*)&Eb[k][ty * 4];
        float4 bv = *(const float4*)&W1e[k][tx * 4];
        mm4x4(acc, a, bv);
    }
    #pragma unroll
    for (int r = 0; r < 4; ++r) {                     // consume q after GEMM
        acc[r][0] += qv[r].x; acc[r][1] += qv[r].y;
        acc[r][2] += qv[r].z; acc[r][3] += qv[r].w;
    }
    #pragma unroll
    for (int r = 0; r < 4; ++r) {                     // run-length carry
        bool act = (c0 + ty * 4 + r) < eEnd;
        float w = act ? el.w[r] : 0.f;
        int d = el.d[r];
        float v0 = fmaxf(acc[r][0], 0.f) * w;
        float v1 = fmaxf(acc[r][1], 0.f) * w;
        float v2 = fmaxf(acc[r][2], 0.f) * w;
        float v3 = fmaxf(acc[r][3], 0.f) * w;
        if (d != run.d) {
            if (run.d >= 0) flush_run(Sacc, run, d0, tx);
            run.d = d; run.s0 = v0; run.s1 = v1; run.s2 = v2; run.s3 = v3;
        } else {
            run.s0 += v0; run.s1 += v1; run.s2 += v2; run.s3 += v3;
        }
    }
}

// One pipeline step for chunk c. Entry: elX/pvX ready for c; mY/speY=perm(c+1),
// elY=el(c+1) arrived; Et[buf]=ef(c). Exit: X holds perm/el(c+2) in flight,
// pvY=p(c+1) in flight, Et[buf^1]=ef(c+1); buf flipped. ONE barrier.
__device__ __forceinline__ void step(int c0, int eEnd, int d0, int& buf,
    Meta& mX, int& speX, El& elX, Pv& pvX,
    Meta& mY, int& speY, El& elY, Pv& pvY,
    const int* __restrict__ perm, const int2* __restrict__ el2,
    const float* __restrict__ ew, const float4* __restrict__ ef4,
    const float4* __restrict__ p4, const float4* __restrict__ q4,
    float (*Et)[16][68], const float (*W1e)[64], float (*Sacc)[68],
    int tid, int ty, int tx, Run& run)
{
    float4 efv = ef4[(size_t)speY * 4 + (tid & 3)];     // ef(c+1) in flight
    load_p(pvY, elY, p4, tx);                           // p(c+1) in flight
    load_perm(mX, speX, c0 + 128, eEnd, ty, tid, perm); // perm(c+2) in flight
    compute_chunk(elX, pvX, c0, eEnd, d0, Et[buf], W1e, Sacc, q4, ty, tx, run);
    load_el(elX, mX, el2, ew);                          // el(c+2) in flight
    stage_ef(Et[buf ^ 1], efv, tid);                    // waits only on efv
    __syncthreads();
    buf ^= 1;
}

__global__ __launch_bounds__(256) void k_edge5(
    const int* __restrict__ perm, const int* __restrict__ ends,
    const int2* __restrict__ el2, const float* __restrict__ ew,
    const float* __restrict__ ef,
    const float* __restrict__ p, const float* __restrict__ q,
    const float* __restrict__ w1e, float* __restrict__ S, int n_nodes)
{
    __shared__ __align__(16) float W1e[16][64];    // 4 KB
    __shared__ __align__(16) float Sacc[64][68];   // 17.4 KB
    __shared__ __align__(16) float Et[2][16][68];  // 8.7 KB dbuf ef tile
    const int tid = threadIdx.x;
    int b = blockIdx.x;
    {   // bijective XCD-chunked swizzle (any nb)
        const int nb = gridDim.x;
        const int qn = nb >> 3, rr = nb & 7;
        const int xcd = b & 7, idx = b >> 3;
        b = (xcd < rr ? xcd * (qn + 1) : rr * (qn + 1) + (xcd - rr) * qn) + idx;
    }
    const int d0 = b * 64;
    const int dn = min(64, n_nodes - d0);
    const int eStart = (d0 == 0) ? 0 : ends[d0 - 1];
    const int eEnd   = ends[d0 + dn - 1];
    const int nc = (eEnd - eStart + 63) >> 6;

    const float4* p4  = (const float4*)p;
    const float4* q4  = (const float4*)q;
    const float4* ef4 = (const float4*)ef;

    ((float4*)W1e)[tid] = ((const float4*)w1e)[tid];
    for (int i = tid; i < 64 * 17; i += 256)
        ((float4*)Sacc)[i] = make_float4(0.f, 0.f, 0.f, 0.f);

    const int ty = tid >> 4, tx = tid & 15;
    Run run; run.d = -1; run.s0 = run.s1 = run.s2 = run.s3 = 0.f;

    if (nc > 0) {
        Meta mX, mY; int speX, speY;
        El elX, elY;
        Pv pvX, pvY;
        // prologue: chunk0 full chain; chunk1 perm+el
        load_perm(mX, speX, eStart, eEnd, ty, tid, perm);
        load_el(elX, mX, el2, ew);
        float4 ef0 = ef4[(size_t)speX * 4 + (tid & 3)];
        load_p(pvX, elX, p4, tx);
        load_perm(mY, speY, eStart + 64, eEnd, ty, tid, perm);
        load_el(elY, mY, el2, ew);
        stage_ef(Et[0], ef0, tid);
        __syncthreads();   // covers W1e, Sacc zero, Et[0]

        int buf = 0;
        for (int c = 0; c < nc; c += 2) {
            step(eStart + (c << 6), eEnd, d0, buf,
                 mX, speX, elX, pvX, mY, speY, elY, pvY,
                 perm, el2, ew, ef4, p4, q4, Et, W1e, Sacc, tid, ty, tx, run);
            if (c + 1 < nc)
                step(eStart + ((c + 1) << 6), eEnd, d0, buf,
                     mY, speY, elY, pvY, mX, speX, elX, pvX,
                     perm, el2, ew, ef4, p4, q4, Et, W1e, Sacc, tid, ty, tx, run);
        }
    }
    if (run.d >= 0) flush_run(Sacc, run, d0, tx);
    __syncthreads();
    for (int i = tid; i < dn * 16; i += 256) {
        int row = i >> 4, f4 = i & 15;
        ((float4*)S)[(size_t)(d0 + row) * 16 + f4] = *(const float4*)&Sacc[row][f4 * 4];
    }
}

// fallback (no-sort tier): tile kernel with global atomics
__global__ __launch_bounds__(256) void k_edge2(
    const int* __restrict__ perm, const int2* __restrict__ el2,
    const float* __restrict__ ew, const float* __restrict__ ef,
    const float* __restrict__ p, const float* __restrict__ q,
    const float* __restrict__ w1e, float* __restrict__ S, int n_edges)
{
    __shared__ __align__(16) float Et[16][68];
    __shared__ __align__(16) float W1e[16][64];
    __shared__ int Ssrc[64];
    __shared__ int Sdst[64];
    __shared__ float Sew[64];
    const int tid = threadIdx.x;
    const int b = blockIdx.x, nb = gridDim.x;
    const int tile = ((nb & 7) == 0) ? ((b & 7) * (nb >> 3) + (b >> 3)) : b;
    const int e0 = tile * 64;
    if (tid < 64) {
        int e = e0 + tid;
        int s = 0, d = 0; float w = 0.f;
        if (e < n_edges) {
            int pe = perm ? perm[e] : e;
            int2 sd = el2[pe];
            s = sd.x; d = sd.y; w = ew[pe];
        }
        Ssrc[tid] = s; Sdst[tid] = d; Sew[tid] = w;
    }
    ((float4*)W1e)[tid] = ((const float4*)w1e)[tid];
    {
        int e = tid >> 2, f4 = tid & 3, k4 = f4 * 4;
        int ge = e0 + e;
        float4 v = make_float4(0.f, 0.f, 0.f, 0.f);
        if (ge < n_edges) {
            int pe = perm ? perm[ge] : ge;
            v = ((const float4*)ef)[(size_t)pe * 4 + f4];
        }
        Et[k4 + 0][e] = v.x; Et[k4 + 1][e] = v.y; Et[k4 + 2][e] = v.z; Et[k4 + 3][e] = v.w;
    }
    __syncthreads();
    const int ty = tid >> 4, tx = tid & 15;
    float acc[4][4];
    #pragma unroll
    for (int r = 0; r < 4; ++r) {
        int s = Ssrc[ty * 4 + r], d = Sdst[ty * 4 + r];
        float4 pv = ((const float4*)p)[(size_t)s * 16 + tx];
        float4 qv = ((const float4*)q)[(size_t)d * 16 + tx];
        acc[r][0] = pv.x + qv.x; acc[r][1] = pv.y + qv.y;
        acc[r][2] = pv.z + qv.z; acc[r][3] = pv.w + qv.w;
    }
    #pragma unroll
    for (int k = 0; k < 16; ++k) {
        float4 a = *(const float4*)&Et[k][ty * 4];
        float4 bv = *(const float4*)&W1e[k][tx * 4];
        mm4x4(acc, a, bv);
    }
    {
        int curd = -1;
        float s0 = 0.f, s1 = 0.f, s2 = 0.f, s3 = 0.f;
        #pragma unroll
        for (int r = 0; r < 4; ++r) {
            int le = ty * 4 + r;
            int ge = e0 + le;
            if (ge < n_edges) {
                int d = Sdst[le];
                float w = Sew[le];
                float v0 = fmaxf(acc[r][0], 0.f) * w;
                float v1 = fmaxf(acc[r][1], 0.f) * w;
                float v2 = fmaxf(acc[r][2], 0.f) * w;
                float v3 = fmaxf(acc[r][3], 0.f) * w;
                if (d != curd) {
                    if (curd >= 0) {
                        atomicAdd(&S[(size_t)curd * 64 + tx * 4 + 0], s0);
                        atomicAdd(&S[(size_t)curd * 64 + tx * 4 + 1], s1);
                        atomicAdd(&S[(size_t)curd * 64 + tx * 4 + 2], s2);
                        atomicAdd(&S[(size_t)curd * 64 + tx * 4 + 3], s3);
                    }
                    curd = d; s0 = v0; s1 = v1; s2 = v2; s3 = v3;
                } else {
                    s0 += v0; s1 += v1; s2 += v2; s3 += v3;
                }
            }
        }
        if (curd >= 0) {
            atomicAdd(&S[(size_t)curd * 64 + tx * 4 + 0], s0);
            atomicAdd(&S[(size_t)curd * 64 + tx * 4 + 1], s1);
            atomicAdd(&S[(size_t)curd * 64 + tx * 4 + 2], s2);
            atomicAdd(&S[(size_t)curd * 64 + tx * 4 + 3], s3);
        }
    }
}

// h = relu(relu(h@U1a + S@C + sw*db + ub1)@uw2 + ub2); optional fused graph segsum
__global__ __launch_bounds__(256) void k_update(
    float* __restrict__ h, const float* __restrict__ S,
    const float* __restrict__ w1, const float* __restrict__ C,
    const float* __restrict__ b1, const float* __restrict__ w2,
    const float* __restrict__ b2, const float* __restrict__ db,
    const float* __restrict__ sw,
    int n, int write_out, float* __restrict__ out_graph,
    const int* __restrict__ n2g)
{
    __shared__ __align__(16) float At[64][68];
    __shared__ __align__(16) float B1[128][64];
    __shared__ float Db[64];
    const int tid = threadIdx.x;
    const int m0 = blockIdx.x * 64;
    const int ty = tid >> 4, tx = tid & 15;
    if (tid < 64) Db[tid] = db[tid];
    for (int i = tid; i < 2048; i += 256)
        ((float4*)B1)[i] = (i < 1024) ? ((const float4*)w1)[i] : ((const float4*)C)[i - 1024];
    for (int i = tid; i < 1024; i += 256) {
        int m = i >> 4, f4 = i & 15, k4 = f4 * 4;
        int node = m0 + m;
        float4 v = make_float4(0.f, 0.f, 0.f, 0.f);
        if (node < n) v = ((const float4*)h)[node * 16 + f4];
        At[k4 + 0][m] = v.x; At[k4 + 1][m] = v.y; At[k4 + 2][m] = v.z; At[k4 + 3][m] = v.w;
    }
    __syncthreads();
    float acc[4][4];
    {
        float4 bb = ((const float4*)b1)[tx];
        #pragma unroll
        for (int r = 0; r < 4; ++r) { acc[r][0]=bb.x; acc[r][1]=bb.y; acc[r][2]=bb.z; acc[r][3]=bb.w; }
    }
    #pragma unroll 8
    for (int k = 0; k < 64; ++k) {
        float4 a = *(const float4*)&At[k][ty * 4];
        float4 bv = *(const float4*)&B1[k][tx * 4];
        mm4x4(acc, a, bv);
    }
    __syncthreads();
    for (int i = tid; i < 1024; i += 256) {
        int m = i >> 4, f4 = i & 15, k4 = f4 * 4;
        int node = m0 + m;
        float4 v = make_float4(0.f, 0.f, 0.f, 0.f);
        if (node < n) v = ((const float4*)S)[node * 16 + f4];
        At[k4 + 0][m] = v.x; At[k4 + 1][m] = v.y; At[k4 + 2][m] = v.z; At[k4 + 3][m] = v.w;
    }
    __syncthreads();
    #pragma unroll 8
    for (int k = 0; k < 64; ++k) {
        float4 a = *(const float4*)&At[k][ty * 4];
        float4 bv = *(const float4*)&B1[64 + k][tx * 4];
        mm4x4(acc, a, bv);
    }
    #pragma unroll
    for (int r = 0; r < 4; ++r) {
        int node = m0 + ty * 4 + r;
        float swv = (node < n) ? sw[node] : 0.f;
        #pragma unroll
        for (int c = 0; c < 4; ++c)
            acc[r][c] = fmaf(swv, Db[tx * 4 + c], acc[r][c]);
    }
    __syncthreads();
    #pragma unroll
    for (int r = 0; r < 4; ++r)
        #pragma unroll
        for (int c = 0; c < 4; ++c)
            At[tx * 4 + c][ty * 4 + r] = fmaxf(acc[r][c], 0.f);
    for (int i = tid; i < 1024; i += 256)
        ((float4*)B1)[i] = ((const float4*)w2)[i];
    __syncthreads();
    float acc2[4][4];
    {
        float4 bb = ((const float4*)b2)[tx];
        #pragma unroll
        for (int r = 0; r < 4; ++r) { acc2[r][0]=bb.x; acc2[r][1]=bb.y; acc2[r][2]=bb.z; acc2[r][3]=bb.w; }
    }
    #pragma unroll 8
    for (int k = 0; k < 64; ++k) {
        float4 a = *(const float4*)&At[k][ty * 4];
        float4 bv = *(const float4*)&B1[k][tx * 4];
        mm4x4(acc2, a, bv);
    }
    float hv[4][4];
    #pragma unroll
    for (int r = 0; r < 4; ++r)
        #pragma unroll
        for (int c = 0; c < 4; ++c)
            hv[r][c] = fmaxf(acc2[r][c], 0.f);
    #pragma unroll
    for (int r = 0; r < 4; ++r) {
        int node = m0 + ty * 4 + r;
        if (node < n)
            ((float4*)h)[node * 16 + tx] = make_float4(hv[r][0], hv[r][1], hv[r][2], hv[r][3]);
    }
    if (write_out) {
        int curg = -1;
        float s0 = 0.f, s1 = 0.f, s2 = 0.f, s3 = 0.f;
        #pragma unroll
        for (int r = 0; r < 4; ++r) {
            int node = m0 + ty * 4 + r;
            if (node < n) {
                int g = n2g[node];
                if (g != curg) {
                    if (curg >= 0) {
                        atomicAdd(&out_graph[curg * 64 + tx * 4 + 0], s0);
                        atomicAdd(&out_graph[curg * 64 + tx * 4 + 1], s1);
                        atomicAdd(&out_graph[curg * 64 + tx * 4 + 2], s2);
                        atomicAdd(&out_graph[curg * 64 + tx * 4 + 3], s3);
                    }
                    curg = g; s0 = hv[r][0]; s1 = hv[r][1]; s2 = hv[r][2]; s3 = hv[r][3];
                } else {
                    s0 += hv[r][0]; s1 += hv[r][1]; s2 += hv[r][2]; s3 += hv[r][3];
                }
            }
        }
        if (curg >= 0) {
            atomicAdd(&out_graph[curg * 64 + tx * 4 + 0], s0);
            atomicAdd(&out_graph[curg * 64 + tx * 4 + 1], s1);
            atomicAdd(&out_graph[curg * 64 + tx * 4 + 2], s2);
            atomicAdd(&out_graph[curg * 64 + tx * 4 + 3], s3);
        }
    }
}

extern "C" void kernel_launch(void* const* d_in, const int* in_sizes, int n_in,
                              void* d_out, int out_size, void* d_ws, size_t ws_size,
                              hipStream_t stream)
{
    const float* x       = (const float*)d_in[0];
    const int2*  el2     = (const int2*)d_in[1];
    const int*   nsc     = (const int*)d_in[2];
    const float* ef      = (const float*)d_in[3];
    const float* ew      = (const float*)d_in[4];
    const int*   n2g     = (const int*)d_in[5];
    const float* lin_w   = (const float*)d_in[7];
    const float* lin_b   = (const float*)d_in[8];
    const float* msg_w1  = (const float*)d_in[9];
    const float* msg_b1  = (const float*)d_in[10];
    const float* msg_w2  = (const float*)d_in[11];
    const float* upd_w1  = (const float*)d_in[13];
    const float* upd_b1  = (const float*)d_in[14];
    const float* upd_w2  = (const float*)d_in[15];
    const float* upd_b2  = (const float*)d_in[16];
    const float* msg_b2  = (const float*)d_in[12];

    float* out_graph = (float*)d_out;              // 128*64
    float* h   = (float*)d_out + 128 * 64;         // node_feature region doubles as h

    const size_t NNH = (size_t)NN * HID;
    float* p  = (float*)d_ws;                     // 25.6 MB
    float* q  = p + NNH;                          // 25.6 MB
    float* S  = q + NNH;                          // 25.6 MB
    char*  cur = (char*)(S + NNH);
    const size_t base   = 3 * NNH * sizeof(float);         // 76.8 MB
    const size_t szPerm = (size_t)NE * sizeof(int);        //  6.4 MB
    const size_t szCnt  = (size_t)NN * sizeof(int);        //  0.4 MB
    const size_t szSw   = (size_t)NN * sizeof(float);      //  0.4 MB
    const size_t szBlk  = 4096;
    const size_t szC    = 2 * 64 * 64 * sizeof(float);     // 32 KB
    const size_t szDb   = 2 * 64 * sizeof(float);
    const size_t need_sort = base + szPerm + szCnt + szBlk + szSw + szC + szDb; // ~84.04 MB

    int *perm = nullptr, *counts = nullptr, *blksum = nullptr;
    float *sw, *C2, *db2;
    const int do_sort = (ws_size >= need_sort) ? 1 : 0;
    if (do_sort) {
        perm   = (int*)cur;        cur += szPerm;
        counts = (int*)cur;        cur += szCnt;
        blksum = (int*)cur;        cur += szBlk;
    }
    sw  = (float*)cur;             cur += szSw;
    C2  = (float*)cur;             cur += szC;
    db2 = (float*)cur;

    const int nblk_n  = (NN + 63) / 64;            // 1563
    const int nblk_e  = (NE + 63) / 64;
    const int nblk_eh = (NE + 255) / 256;
    const int nblk_sc = (NN + 255) / 256;          // 391 <= 512

    hipMemsetAsync(d_out, 0, 128 * 64 * sizeof(float), stream);
    hipMemsetAsync(sw, 0, szSw, stream);

    if (do_sort) {
        hipMemsetAsync(counts, 0, szCnt, stream);
        k_hist2<<<nblk_eh, 256, 0, stream>>>(el2, ew, counts, sw, NE);   // dst key + fused sw
        k_scan1<<<nblk_sc, 256, 0, stream>>>(counts, counts, blksum, NN);
        k_scan2<<<1, 512, 0, stream>>>(blksum, nblk_sc);
        k_scan3<<<nblk_sc, 256, 0, stream>>>(counts, blksum, NN);
        k_permute<<<nblk_eh, 256, 0, stream>>>(el2, counts, perm, NE);
        // counts[d] now == CSR end offset of dst d
    } else {
        k_sw<<<nblk_eh, 256, 0, stream>>>(el2, ew, sw, NE);
    }
    k_csmall<<<2, 256, 0, stream>>>(msg_w2, upd_w1, msg_b2, C2, db2);

    k_init<<<nblk_n, 256, 0, stream>>>(x, lin_w, lin_b, h, NN);
    for (int l = 0; l < 2; ++l) {
        const float* w1 = msg_w1 + (size_t)l * MSG_IN * HID;
        k_pq<<<nblk_n, 256, 0, stream>>>(h, nsc, w1, msg_b1 + l * HID, p, q, NN);
        if (do_sort) {
            k_edge5<<<nblk_n, 256, 0, stream>>>(perm, counts, el2, ew, ef, p, q,
                                                w1 + W1E_OFF * HID, S, NN);
        } else {
            hipMemsetAsync(S, 0, NNH * sizeof(float), stream);
            k_edge2<<<nblk_e, 256, 0, stream>>>(nullptr, el2, ew, ef, p, q,
                                                w1 + W1E_OFF * HID, S, NE);
        }
        k_update<<<nblk_n, 256, 0, stream>>>(h, S,
                                             upd_w1 + (size_t)l * 2 * HID * HID,
                                             C2 + (size_t)l * 4096,
                                             upd_b1 + l * HID,
                                             upd_w2 + (size_t)l * HID * HID,
                                             upd_b2 + l * HID,
                                             db2 + l * 64, sw,
                                             NN, (l == 1) ? 1 : 0, out_graph, n2g);
    }
}